// Round 11
// baseline (87.892 us; speedup 1.0000x reference)
//
#include <hip/hip_runtime.h>

#define RNK 32
#define VOC 32000
#define BSZ 512
#define SEQ 24

#define RED_BLOCKS 4000           // 32 r-slabs x 125 chunks (256 v each)
#define RED_THREADS 256
#define DEPTH 4                   // tokens in flight per chain wave
#define NSLOT 5                   // DEPTH+1 -> rotation never aliases (absmax-0 proven)

// ws layout (floats): gm[1024] | bitmap[1024] | rank_word[1024] | staged[12288*1024]
#define WS_NEEDED ((size_t)(3 * 1024) * 4 + (size_t)BSZ * SEQ * 1024 * 4)

typedef const __attribute__((address_space(1))) void* as1_cvp;
typedef __attribute__((address_space(3))) void* as3_vp;

// Scattered staging (fallback path): quad-XOR source swizzle [R9-proven].
__device__ __forceinline__ void issue_scat(const float* src_tok, float* lds_base, int lane) {
    const int rlo = lane >> 3;
    const int cq  = ((lane & 7) ^ rlo) * 4;
    #pragma unroll
    for (int j = 0; j < 4; ++j) {
        const float* src = src_tok + (size_t)(j * 8 + rlo) * ((size_t)VOC * RNK) + cq;
        __builtin_amdgcn_global_load_lds((as1_cvp)src, (as3_vp)(lds_base + j * 256), 16, 0, 0);
    }
}
// Contiguous staging (staged[] is already swizzled in memory): pure linear copy.
__device__ __forceinline__ void issue_lin(const float* src4k, float* lds_base, int lane) {
    #pragma unroll
    for (int j = 0; j < 4; ++j) {
        __builtin_amdgcn_global_load_lds((as1_cvp)(src4k + j * 256 + lane * 4),
                                         (as3_vp)(lds_base + j * 256), 16, 0, 0);
    }
}

// ---------------------------------------------------------------------------
// Setup: token bitmap (1024 words >= 32000 bits) + exclusive per-word rank
// prefix. One block, LDS-only; ~2-3 us.
// ---------------------------------------------------------------------------
__global__ __launch_bounds__(256) void setup_kernel(const int* __restrict__ y,
                                                    unsigned* __restrict__ bitmap,
                                                    int* __restrict__ rank_word) {
    __shared__ unsigned lbit[1024];
    __shared__ int tsum[256];
    const int tid = threadIdx.x;
    #pragma unroll
    for (int j = 0; j < 4; ++j) lbit[tid * 4 + j] = 0u;
    __syncthreads();
    #pragma unroll
    for (int k = 0; k < 48; ++k) {            // 256*48 = 12288 tokens
        const int tok = y[tid * 48 + k];
        atomicOr(&lbit[tok >> 5], 1u << (tok & 31));
    }
    __syncthreads();
    int c[4], s = 0;
    #pragma unroll
    for (int j = 0; j < 4; ++j) { c[j] = __popc(lbit[tid * 4 + j]); s += c[j]; }
    tsum[tid] = s;
    __syncthreads();
    for (int off = 1; off < 256; off <<= 1) { // Hillis-Steele inclusive scan
        int v = (tid >= off) ? tsum[tid - off] : 0;
        __syncthreads();
        tsum[tid] += v;
        __syncthreads();
    }
    int run = tsum[tid] - s;                  // exclusive prefix of this 4-word group
    #pragma unroll
    for (int j = 0; j < 4; ++j) {
        rank_word[tid * 4 + j] = run;
        run += c[j];
        bitmap[tid * 4 + j] = lbit[tid * 4 + j];
    }
}

// ---------------------------------------------------------------------------
// Reduce + stage: stream core (gm partials, register butterfly, 32 atomics per
// wave) and export used tokens' rows into staged[rank][r][swizzled quads] as
// coalesced 128B stores. stage_en=0 -> plain reduce (fallback).
// ---------------------------------------------------------------------------
__global__ __launch_bounds__(RED_THREADS) void reduce_stage_kernel(const float* __restrict__ core,
                                                                   float* __restrict__ gm,
                                                                   const unsigned* __restrict__ bitmap,
                                                                   const int* __restrict__ rank_word,
                                                                   float* __restrict__ staged,
                                                                   int stage_en) {
    const int bid   = blockIdx.x;
    const int r     = bid & 31;
    const int chunk = bid >> 5;               // 0..124
    const int tid   = threadIdx.x;

    const float4* slab = (const float4*)(core + (size_t)r * VOC * RNK);
    const int base = chunk * 2048 + tid;      // float4 index; 32 KB per block

    float a0 = 0.f, a1 = 0.f, a2 = 0.f, a3 = 0.f;
    #pragma unroll
    for (int i = 0; i < 8; ++i) {
        float4 v = slab[base + i * 256];
        a0 += v.x; a1 += v.y; a2 += v.z; a3 += v.w;
    }

    // s-phase (tid*4)%32 = (tid&7)*4 invariant under xor 8/16/32 [R8-proven].
    #pragma unroll
    for (int mask = 8; mask <= 32; mask <<= 1) {
        a0 += __shfl_xor(a0, mask, 64);
        a1 += __shfl_xor(a1, mask, 64);
        a2 += __shfl_xor(a2, mask, 64);
        a3 += __shfl_xor(a3, mask, 64);
    }
    if ((tid & 63) < 8) {
        const int s0 = (tid & 7) * 4;
        atomicAdd(&gm[r * RNK + s0 + 0], a0);
        atomicAdd(&gm[r * RNK + s0 + 1], a1);
        atomicAdd(&gm[r * RNK + s0 + 2], a2);
        atomicAdd(&gm[r * RNK + s0 + 3], a3);
    }

    if (stage_en) {
        // 32 groups of 8 lanes; group g serially checks v = vbase + g*8 + k.
        const int gid = tid >> 3, li = tid & 7;
        const int vbase = chunk * 256;
        #pragma unroll
        for (int k = 0; k < 8; ++k) {
            const int v = vbase + gid * 8 + k;
            const unsigned w = bitmap[v >> 5];
            if (w & (1u << (v & 31))) {
                const int rk = rank_word[v >> 5] + __popc(w & ((1u << (v & 31)) - 1u));
                // source row is L2-hot (just streamed); write pre-swizzled quad
                const float4 val = *(const float4*)(core + ((size_t)r * VOC + v) * RNK + li * 4);
                *(float4*)(staged + (size_t)rk * 1024 + r * 32 + ((li ^ (r & 7)) << 2)) = val;
            }
        }
    }
}

// ---------------------------------------------------------------------------
// Chain (+z in block BSZ). linear=1: contiguous 4KB fetches from staged[];
// linear=0: scattered fetches from core (fallback). Both fill the same
// swizzled LDS layout; la[] table + DEPTH/NSLOT schedule are [R8/R9-proven].
// ---------------------------------------------------------------------------
__global__ __launch_bounds__(64) void chainz_kernel(const float* __restrict__ core,
                                                    const float* __restrict__ staged,
                                                    const int* __restrict__ y,
                                                    const unsigned* __restrict__ bitmap,
                                                    const int* __restrict__ rank_word,
                                                    const float* __restrict__ alpha,
                                                    const float* __restrict__ beta,
                                                    float* __restrict__ out,
                                                    const float* __restrict__ gm,
                                                    int linear) {
    __shared__ float mbuf[NSLOT * 1024];      // 20 KB
    const int tid = threadIdx.x;              // == lane (1 wave/block)

    if (blockIdx.x < BSZ) {
        const int lane = tid;
        const int s    = lane & 31;
        const int half = lane >> 5;
        const int row  = blockIdx.x;

        int ytok = 0, rtok = 0;
        if (lane < SEQ) {
            ytok = y[row * SEQ + lane];
            const unsigned w = bitmap[ytok >> 5];
            rtok = rank_word[ytok >> 5] + __popc(w & ((1u << (ytok & 31)) - 1u));
        }
        float state = alpha[s];
        float betav = beta[s];

        // swizzled LDS float-offsets: read M[r=16h+i][s]
        int la[16];
        #pragma unroll
        for (int i = 0; i < 16; ++i) {
            const int r = half * 16 + i;
            la[i] = r * 32 + (((s >> 2) ^ (r & 7)) << 2) + (s & 3);
        }

        asm volatile("s_waitcnt vmcnt(0)" ::: "memory");  // drain; vmcnt counts gl_lds only

        #pragma unroll
        for (int pt = 0; pt < DEPTH; ++pt) {  // prologue: tokens 0..3 -> slots 0..3
            const int tok = __shfl(ytok, pt, 64);
            const int rk  = __shfl(rtok, pt, 64);
            if (linear) issue_lin(staged + (size_t)rk * 1024, mbuf + pt * 1024, lane);
            else        issue_scat(core + (size_t)tok * RNK, mbuf + pt * 1024, lane);
        }

        #pragma unroll
        for (int t = 0; t < SEQ; ++t) {       // fully unrolled -> literal waits
            if      (t <= SEQ - 4) asm volatile("s_waitcnt vmcnt(12)" ::: "memory");
            else if (t == SEQ - 3) asm volatile("s_waitcnt vmcnt(8)"  ::: "memory");
            else if (t == SEQ - 2) asm volatile("s_waitcnt vmcnt(4)"  ::: "memory");
            else                   asm volatile("s_waitcnt vmcnt(0)"  ::: "memory");
            __builtin_amdgcn_sched_barrier(0);

            const float* M = mbuf + (t % NSLOT) * 1024;
            float a0 = 0.f, a1 = 0.f, a2 = 0.f, a3 = 0.f;
            #pragma unroll
            for (int i = 0; i < 16; i += 4) {
                a0 = fmaf(__shfl(state, half * 16 + i + 0, 64), M[la[i + 0]], a0);
                a1 = fmaf(__shfl(state, half * 16 + i + 1, 64), M[la[i + 1]], a1);
                a2 = fmaf(__shfl(state, half * 16 + i + 2, 64), M[la[i + 2]], a2);
                a3 = fmaf(__shfl(state, half * 16 + i + 3, 64), M[la[i + 3]], a3);
            }
            const float acc = (a0 + a1) + (a2 + a3);
            state = acc + __shfl_xor(acc, 32, 64);

            if (t + DEPTH < SEQ) {            // refill a slot neither in use nor in flight
                const int tok = __shfl(ytok, t + DEPTH, 64);
                const int rk  = __shfl(rtok, t + DEPTH, 64);
                if (linear) issue_lin(staged + (size_t)rk * 1024,
                                      mbuf + ((t + DEPTH) % NSLOT) * 1024, lane);
                else        issue_scat(core + (size_t)tok * RNK,
                                       mbuf + ((t + DEPTH) % NSLOT) * 1024, lane);
            }
        }

        float p = state * betav;
        #pragma unroll
        for (int m = 16; m >= 1; m >>= 1) p += __shfl_xor(p, m, 64);
        if (lane == 0) out[row] = p;
    } else {
        // ---------------- z: one wave ----------------
        const int s    = tid & 31;
        const int half = tid >> 5;
        float col[16];
        #pragma unroll
        for (int i = 0; i < 16; ++i) col[i] = gm[(half * 16 + i) * RNK + s];
        float v = alpha[s];
        #pragma unroll
        for (int t = 0; t < SEQ; ++t) {
            float a0 = 0.f, a1 = 0.f, a2 = 0.f, a3 = 0.f;
            #pragma unroll
            for (int i = 0; i < 16; i += 4) {
                a0 = fmaf(__shfl(v, half * 16 + i + 0, 64), col[i + 0], a0);
                a1 = fmaf(__shfl(v, half * 16 + i + 1, 64), col[i + 1], a1);
                a2 = fmaf(__shfl(v, half * 16 + i + 2, 64), col[i + 2], a2);
                a3 = fmaf(__shfl(v, half * 16 + i + 3, 64), col[i + 3], a3);
            }
            const float acc = (a0 + a1) + (a2 + a3);
            v = acc + __shfl_xor(acc, 32, 64);
        }
        float z = v * beta[s];
        #pragma unroll
        for (int m = 16; m >= 1; m >>= 1) z += __shfl_xor(z, m, 64);
        if (tid == 0) out[BSZ] = z * (float)BSZ;
    }
}

extern "C" void kernel_launch(void* const* d_in, const int* in_sizes, int n_in,
                              void* d_out, int out_size, void* d_ws, size_t ws_size,
                              hipStream_t stream) {
    const int*   y     = (const int*)d_in[0];
    const float* alpha = (const float*)d_in[1];
    const float* beta  = (const float*)d_in[2];
    const float* core  = (const float*)d_in[3];
    float*    out       = (float*)d_out;
    float*    gm        = (float*)d_ws;                 // 1024 floats
    unsigned* bitmap    = (unsigned*)(gm + 1024);       // 1024 words
    int*      rank_word = (int*)(bitmap + 1024);        // 1024 ints
    float*    staged    = (float*)(rank_word + 1024);   // up to 12288 * 1024 floats

    const int use_staging = (ws_size >= WS_NEEDED) ? 1 : 0;

    hipMemsetAsync(gm, 0, RNK * RNK * sizeof(float), stream);
    if (use_staging) {
        setup_kernel<<<1, 256, 0, stream>>>(y, bitmap, rank_word);
    }
    reduce_stage_kernel<<<RED_BLOCKS, RED_THREADS, 0, stream>>>(
        core, gm, bitmap, rank_word, staged, use_staging);
    chainz_kernel<<<BSZ + 1, 64, 0, stream>>>(
        core, staged, y, bitmap, rank_word, alpha, beta, out, gm, use_staging);
}